// Round 2
// baseline (97.902 us; speedup 1.0000x reference)
//
#include <hip/hip_runtime.h>
#include <hip/hip_bf16.h>
#include <stdint.h>

#define M_DIM 128
#define N_DIM 8192
#define K_DIM 8192
#define KP    4096      // packed int32 per weight row
#define NGRP  64
#define KSPLIT 8
#define KCHUNK (K_DIM / KSPLIT)   // 1024
#define NSTEPS (KCHUNK / 32)      // 32 (even, required by loop structure)

typedef __attribute__((ext_vector_type(8))) short bf16x8;
typedef __attribute__((ext_vector_type(4))) float f32x4;

__device__ __forceinline__ unsigned short f2bf(float f) {
  unsigned int u = __float_as_uint(f);
  return (unsigned short)((u + 0x7fffu + ((u >> 16) & 1u)) >> 16);
}

__global__ void xcast_kernel(const float* __restrict__ x, unsigned short* __restrict__ xb) {
  int idx = (blockIdx.x * blockDim.x + threadIdx.x) * 8;
  const float4* xp = (const float4*)(x + idx);
  float4 a = xp[0], b = xp[1];
  uint4 o;
  o.x = (unsigned)f2bf(a.x) | ((unsigned)f2bf(a.y) << 16);
  o.y = (unsigned)f2bf(a.z) | ((unsigned)f2bf(a.w) << 16);
  o.z = (unsigned)f2bf(b.x) | ((unsigned)f2bf(b.y) << 16);
  o.w = (unsigned)f2bf(b.z) | ((unsigned)f2bf(b.w) << 16);
  *(uint4*)(xb + idx) = o;
}

// LDS-free, barrier-free streaming dequant-GEMM.
// Wave tile: 128(M) x 32(N). Lane l holds B-frag col (l&15), k-chunk (l>>4):
// its 8 nibbles live in the low bytes of 4 consecutive int32 -> one dwordx4.
__global__ __launch_bounds__(256, 2)
void gemm_kernel(const unsigned short* __restrict__ xb,
                 const int* __restrict__ wq,
                 const float* __restrict__ scale,
                 const float* __restrict__ zpt,
                 unsigned short* __restrict__ partial)
{
  const int tid = threadIdx.x;
  const int l   = tid & 63;
  const int w   = tid >> 6;
  const int n0  = blockIdx.x * 128;
  const int ks  = blockIdx.y;
  const int k_base = ks * KCHUNK;

  const int lr = l & 15;   // fragment row/col selector
  const int lk = l >> 4;   // k-chunk selector

  // B-fragment weight rows for this lane (wave covers cols n0+w*32 .. +32)
  const int r0 = n0 + w * 32 + lr;
  const int r1 = r0 + 16;

  f32x4 acc[8][2];
  #pragma unroll
  for (int mi = 0; mi < 8; ++mi)
    #pragma unroll
    for (int ni = 0; ni < 2; ++ni) {
      f32x4 z = {0.f, 0.f, 0.f, 0.f};
      acc[mi][ni] = z;
    }

  const unsigned short* xptr = xb + (size_t)lr * K_DIM + k_base + lk * 8;
  const int* wp0 = wq + (size_t)r0 * KP + (k_base >> 1) + lk * 4;
  const int* wp1 = wq + (size_t)r1 * KP + (k_base >> 1) + lk * 4;

  uint4 avA[8]; int4 bwA[2];
  uint4 avB[8]; int4 bwB[2];
  float sc[2], nz[2];

  auto LOAD = [&](uint4 (&av)[8], int4 (&bw)[2], int t) {
    const int koff = t * 32;  // shorts
    #pragma unroll
    for (int mi = 0; mi < 8; ++mi)
      av[mi] = *(const uint4*)(xptr + (size_t)mi * 16 * K_DIM + koff);
    bw[0] = *(const int4*)(wp0 + t * 16);
    bw[1] = *(const int4*)(wp1 + t * 16);
  };

  auto SCALES = [&](int t) {
    int g = (k_base + t * 32) >> 7;
    float s0 = scale[r0 * NGRP + g], z0 = zpt[r0 * NGRP + g];
    float s1 = scale[r1 * NGRP + g], z1 = zpt[r1 * NGRP + g];
    sc[0] = s0; nz[0] = -z0 * s0;
    sc[1] = s1; nz[1] = -z1 * s1;
  };

  auto STEP = [&](const uint4 (&av)[8], const int4 (&bw)[2]) {
    uint4 bq[2];
    #pragma unroll
    for (int ni = 0; ni < 2; ++ni) {
      int vals[4] = {bw[ni].x, bw[ni].y, bw[ni].z, bw[ni].w};
      unsigned words[4];
      #pragma unroll
      for (int j = 0; j < 4; ++j) {
        int hi = (vals[j] << 24) >> 28;   // bits 7:4 sign-extended (k = 2j)
        int lo = (vals[j] << 28) >> 28;   // bits 3:0 sign-extended (k = 2j+1)
        float fh = fmaf((float)hi, sc[ni], nz[ni]);
        float fl = fmaf((float)lo, sc[ni], nz[ni]);
        unsigned r;
        asm("v_cvt_pk_bf16_f32 %0, %1, %2" : "=v"(r) : "v"(fh), "v"(fl));
        words[j] = r;                     // low16 = k even, high16 = k odd
      }
      uint4 o; o.x = words[0]; o.y = words[1]; o.z = words[2]; o.w = words[3];
      bq[ni] = o;
    }
    #pragma unroll
    for (int mi = 0; mi < 8; ++mi)
      #pragma unroll
      for (int ni = 0; ni < 2; ++ni)
        acc[mi][ni] = __builtin_amdgcn_mfma_f32_16x16x32_bf16(
            __builtin_bit_cast(bf16x8, av[mi]),
            __builtin_bit_cast(bf16x8, bq[ni]),
            acc[mi][ni], 0, 0, 0);
  };

  LOAD(avA, bwA, 0);
  for (int t = 0; t < NSTEPS; t += 2) {
    LOAD(avB, bwB, t + 1);
    if ((t & 3) == 0) SCALES(t);   // group = 128 k = 4 steps; boundary only at even t
    STEP(avA, bwA);
    if (t + 2 < NSTEPS) LOAD(avA, bwA, t + 2);
    STEP(avB, bwB);
  }

  // epilogue: bf16 partial [ks][128][8192]
  unsigned short* p = partial + (size_t)ks * (M_DIM * N_DIM);
  #pragma unroll
  for (int mi = 0; mi < 8; ++mi)
    #pragma unroll
    for (int ni = 0; ni < 2; ++ni) {
      int col = n0 + w * 32 + ni * 16 + lr;
      int rowb = mi * 16 + lk * 4;
      #pragma unroll
      for (int j = 0; j < 4; ++j)
        p[(size_t)(rowb + j) * N_DIM + col] = f2bf(acc[mi][ni][j]);
    }
}

__global__ void reduce_kernel(const unsigned short* __restrict__ part,
                              const float* __restrict__ bias,
                              float* __restrict__ out) {
  int idx = (blockIdx.x * blockDim.x + threadIdx.x) * 8;
  float s[8];
  #pragma unroll
  for (int j = 0; j < 8; ++j) s[j] = 0.f;
  #pragma unroll
  for (int k = 0; k < KSPLIT; ++k) {
    uint4 v = *(const uint4*)(part + (size_t)k * (M_DIM * N_DIM) + idx);
    unsigned ws[4] = {v.x, v.y, v.z, v.w};
    #pragma unroll
    for (int j = 0; j < 4; ++j) {
      s[2 * j]     += __uint_as_float((ws[j] & 0xffffu) << 16);
      s[2 * j + 1] += __uint_as_float((ws[j] & 0xffff0000u));
    }
  }
  int col = idx & (N_DIM - 1);
  float4 b0 = *(const float4*)(bias + col);
  float4 b1 = *(const float4*)(bias + col + 4);
  float4 o0, o1;
  o0.x = s[0] + b0.x; o0.y = s[1] + b0.y; o0.z = s[2] + b0.z; o0.w = s[3] + b0.w;
  o1.x = s[4] + b1.x; o1.y = s[5] + b1.y; o1.z = s[6] + b1.z; o1.w = s[7] + b1.w;
  *(float4*)(out + idx) = o0;
  *(float4*)(out + idx + 4) = o1;
}

extern "C" void kernel_launch(void* const* d_in, const int* in_sizes, int n_in,
                              void* d_out, int out_size, void* d_ws, size_t ws_size,
                              hipStream_t stream) {
  const float* x     = (const float*)d_in[0];
  const int*   wq    = (const int*)d_in[1];
  const float* scale = (const float*)d_in[2];
  const float* zpt   = (const float*)d_in[3];
  const float* bias  = (const float*)d_in[4];
  float* out = (float*)d_out;

  unsigned short* xb = (unsigned short*)d_ws;
  const size_t xbytes = (size_t)M_DIM * K_DIM * 2;                 // 2 MiB
  unsigned short* partial = (unsigned short*)((char*)d_ws + xbytes); // 16 MiB bf16

  xcast_kernel<<<(M_DIM * K_DIM) / (256 * 8), 256, 0, stream>>>(x, xb);
  gemm_kernel<<<dim3(N_DIM / 128, KSPLIT), 256, 0, stream>>>(
      xb, wq, scale, zpt, partial);
  reduce_kernel<<<(M_DIM * N_DIM) / (256 * 8), 256, 0, stream>>>(
      partial, bias, out);
}

// Round 4
// 57.980 us; speedup vs baseline: 1.6885x; 1.6885x over previous
//
#include <hip/hip_runtime.h>
#include <hip/hip_bf16.h>
#include <stdint.h>

#define M_DIM 128
#define N_DIM 8192
#define K_DIM 8192
#define KP    4096      // packed int32 per weight row
#define NGRP  64
#define KSPLIT 8
#define KCHUNK (K_DIM / KSPLIT)   // 1024
#define BK    64
#define NSTEPS (KCHUNK / BK)      // 16 (even)

typedef __attribute__((ext_vector_type(8))) short bf16x8;
typedef __attribute__((ext_vector_type(4))) float f32x4;

__device__ __forceinline__ unsigned short f2bf(float f) {
  unsigned int u = __float_as_uint(f);
  return (unsigned short)((u + 0x7fffu + ((u >> 16) & 1u)) >> 16);
}

__global__ void xcast_kernel(const float* __restrict__ x, unsigned short* __restrict__ xb) {
  int idx = (blockIdx.x * blockDim.x + threadIdx.x) * 8;
  const float4* xp = (const float4*)(x + idx);
  float4 a = xp[0], b = xp[1];
  uint4 o;
  o.x = (unsigned)f2bf(a.x) | ((unsigned)f2bf(a.y) << 16);
  o.y = (unsigned)f2bf(a.z) | ((unsigned)f2bf(a.w) << 16);
  o.z = (unsigned)f2bf(b.x) | ((unsigned)f2bf(b.y) << 16);
  o.w = (unsigned)f2bf(b.z) | ((unsigned)f2bf(b.w) << 16);
  *(uint4*)(xb + idx) = o;
}

// Block tile 128(M) x 128(N), 4 waves; wave w owns cols n0+w*32..+32, all 128 rows.
// x: R1's proven LDS staging (BK=64, ^(row&7) swizzle, global_load_lds).
// W: R2's proven reg-direct path (lane's dwordx4 = its 8 nibbles), dequant in regs.
__global__ __launch_bounds__(256, 2)
void gemm_kernel(const unsigned short* __restrict__ xb,
                 const int* __restrict__ wq,
                 const float* __restrict__ scale,
                 const float* __restrict__ zpt,
                 unsigned short* __restrict__ partial)
{
  __shared__ uint4 xbuf[2][1024];    // [128 rows][8 chunks of 16B], 2 x 16 KB

  const int tid = threadIdx.x;
  const int l   = tid & 63;
  const int w   = tid >> 6;
  const int l15 = l & 15;
  const int lk  = l >> 4;            // 0..3
  const int n0  = blockIdx.x * 128;
  const int ks  = blockIdx.y;
  const int k0  = ks * KCHUNK;

  const int r0 = n0 + w * 32 + l15;  // lane's two weight rows (B-frag cols)
  const int r1 = r0 + 16;
  const int* wp0 = wq + (size_t)r0 * KP + (k0 >> 1) + lk * 4;
  const int* wp1 = wq + (size_t)r1 * KP + (k0 >> 1) + lk * 4;

  f32x4 acc[8][2];
  #pragma unroll
  for (int mi = 0; mi < 8; ++mi)
    #pragma unroll
    for (int ni = 0; ni < 2; ++ni) {
      f32x4 z = {0.f, 0.f, 0.f, 0.f};
      acc[mi][ni] = z;
    }

  int4  wA[2][2], wB[2][2];          // [ni][kk], statically indexed double-buffer
  float scA[2], nzA[2], scB[2], nzB[2];

  // R1-verbatim x staging: linear LDS dest, inverse-swizzled global source
  auto issue_x = [&](int t, int nb) {
    const int kt = k0 + t * BK;
    #pragma unroll
    for (int i = 0; i < 4; ++i) {
      int rloc = i * 32 + w * 8 + (l >> 3);                    // LDS row 0..127
      const unsigned short* src = xb + (size_t)rloc * K_DIM + kt
                                  + (((l & 7) ^ ((l >> 3) & 7)) * 8);
      uint4* dst = &xbuf[nb][(i * 32 + w * 8) * 8];            // wave-uniform base
      __builtin_amdgcn_global_load_lds(
          (__attribute__((address_space(1))) void*)(void*)src,
          (__attribute__((address_space(3))) void*)(void*)dst, 16, 0, 0);
    }
  };

  auto LOADW = [&](int t, int4 (&wr)[2][2], float (&sc)[2], float (&nz)[2]) {
    #pragma unroll
    for (int kk = 0; kk < 2; ++kk) {
      wr[0][kk] = *(const int4*)(wp0 + t * 32 + kk * 16);
      wr[1][kk] = *(const int4*)(wp1 + t * 32 + kk * 16);
    }
    const int g = (k0 + t * BK) >> 7;
    float s0 = scale[r0 * NGRP + g], z0 = zpt[r0 * NGRP + g];
    float s1 = scale[r1 * NGRP + g], z1 = zpt[r1 * NGRP + g];
    sc[0] = s0; nz[0] = -z0 * s0;
    sc[1] = s1; nz[1] = -z1 * s1;
  };

  auto COMPUTE = [&](const uint4* xlds, const int4 (&wr)[2][2],
                     const float (&sc)[2], const float (&nz)[2]) {
    #pragma unroll
    for (int kk = 0; kk < 2; ++kk) {
      const int q = kk * 4 + lk;                 // x chunk 0..7 within BK=64 row
      uint4 av[8];
      #pragma unroll
      for (int mi = 0; mi < 8; ++mi) {
        int r = mi * 16 + l15;
        av[mi] = xlds[r * 8 + (q ^ (r & 7))];    // R1's proven swizzled read
      }
      uint4 bq[2];
      #pragma unroll
      for (int ni = 0; ni < 2; ++ni) {
        int vals[4] = {wr[ni][kk].x, wr[ni][kk].y, wr[ni][kk].z, wr[ni][kk].w};
        unsigned words[4];
        #pragma unroll
        for (int j = 0; j < 4; ++j) {
          int hi = (vals[j] << 24) >> 28;        // bits 7:4 -> k even
          int lo = (vals[j] << 28) >> 28;        // bits 3:0 -> k odd
          float fh = fmaf((float)hi, sc[ni], nz[ni]);
          float fl = fmaf((float)lo, sc[ni], nz[ni]);
          unsigned r;
          asm("v_cvt_pk_bf16_f32 %0, %1, %2" : "=v"(r) : "v"(fh), "v"(fl));
          words[j] = r;
        }
        uint4 o; o.x = words[0]; o.y = words[1]; o.z = words[2]; o.w = words[3];
        bq[ni] = o;
      }
      #pragma unroll
      for (int mi = 0; mi < 8; ++mi)
        #pragma unroll
        for (int ni = 0; ni < 2; ++ni)
          acc[mi][ni] = __builtin_amdgcn_mfma_f32_16x16x32_bf16(
              __builtin_bit_cast(bf16x8, av[mi]),
              __builtin_bit_cast(bf16x8, bq[ni]),
              acc[mi][ni], 0, 0, 0);
    }
  };

  // prologue
  issue_x(0, 0);
  LOADW(0, wA, scA, nzA);
  __syncthreads();

  for (int t = 0; t < NSTEPS; t += 2) {          // no unroll pragma (match R1)
    issue_x(t + 1, 1);
    LOADW(t + 1, wB, scB, nzB);
    COMPUTE(&xbuf[0][0], wA, scA, nzA);
    __syncthreads();
    if (t + 2 < NSTEPS) {
      issue_x(t + 2, 0);
      LOADW(t + 2, wA, scA, nzA);
    }
    COMPUTE(&xbuf[1][0], wB, scB, nzB);
    __syncthreads();
  }

  // epilogue: R2-verbatim bf16 partial [ks][s][o]
  unsigned short* p = partial + (size_t)ks * (M_DIM * N_DIM);
  #pragma unroll
  for (int mi = 0; mi < 8; ++mi)
    #pragma unroll
    for (int ni = 0; ni < 2; ++ni) {
      int col = n0 + w * 32 + ni * 16 + l15;
      int rowb = mi * 16 + lk * 4;
      #pragma unroll
      for (int j = 0; j < 4; ++j)
        p[(size_t)(rowb + j) * N_DIM + col] = f2bf(acc[mi][ni][j]);
    }
}

// R2-verbatim reduce over ksplit + bias
__global__ void reduce_kernel(const unsigned short* __restrict__ part,
                              const float* __restrict__ bias,
                              float* __restrict__ out) {
  int idx = (blockIdx.x * blockDim.x + threadIdx.x) * 8;
  float s[8];
  #pragma unroll
  for (int j = 0; j < 8; ++j) s[j] = 0.f;
  #pragma unroll
  for (int k = 0; k < KSPLIT; ++k) {
    uint4 v = *(const uint4*)(part + (size_t)k * (M_DIM * N_DIM) + idx);
    unsigned ws[4] = {v.x, v.y, v.z, v.w};
    #pragma unroll
    for (int j = 0; j < 4; ++j) {
      s[2 * j]     += __uint_as_float((ws[j] & 0xffffu) << 16);
      s[2 * j + 1] += __uint_as_float(ws[j] & 0xffff0000u);
    }
  }
  int col = idx & (N_DIM - 1);
  float4 b0 = *(const float4*)(bias + col);
  float4 b1 = *(const float4*)(bias + col + 4);
  float4 o0, o1;
  o0.x = s[0] + b0.x; o0.y = s[1] + b0.y; o0.z = s[2] + b0.z; o0.w = s[3] + b0.w;
  o1.x = s[4] + b1.x; o1.y = s[5] + b1.y; o1.z = s[6] + b1.z; o1.w = s[7] + b1.w;
  *(float4*)(out + idx) = o0;
  *(float4*)(out + idx + 4) = o1;
}

extern "C" void kernel_launch(void* const* d_in, const int* in_sizes, int n_in,
                              void* d_out, int out_size, void* d_ws, size_t ws_size,
                              hipStream_t stream) {
  const float* x     = (const float*)d_in[0];
  const int*   wq    = (const int*)d_in[1];
  const float* scale = (const float*)d_in[2];
  const float* zpt   = (const float*)d_in[3];
  const float* bias  = (const float*)d_in[4];
  float* out = (float*)d_out;

  unsigned short* xb = (unsigned short*)d_ws;
  const size_t xbytes = (size_t)M_DIM * K_DIM * 2;                   // 2 MiB
  unsigned short* partial = (unsigned short*)((char*)d_ws + xbytes); // 16 MiB bf16

  xcast_kernel<<<(M_DIM * K_DIM) / (256 * 8), 256, 0, stream>>>(x, xb);
  gemm_kernel<<<dim3(N_DIM / 128, KSPLIT), 256, 0, stream>>>(
      xb, wq, scale, zpt, partial);
  reduce_kernel<<<(M_DIM * N_DIM) / (256 * 8), 256, 0, stream>>>(
      partial, bias, out);
}

// Round 5
// 57.083 us; speedup vs baseline: 1.7151x; 1.0157x over previous
//
#include <hip/hip_runtime.h>
#include <hip/hip_bf16.h>
#include <stdint.h>

#define M_DIM 128
#define N_DIM 8192
#define K_DIM 8192
#define KP    4096      // packed int32 per weight row
#define NGRP  64
#define KSPLIT 8
#define KCHUNK (K_DIM / KSPLIT)   // 1024
#define BK    64
#define NSTEPS (KCHUNK / BK)      // 16 (even)

typedef __attribute__((ext_vector_type(8))) short bf16x8;
typedef __attribute__((ext_vector_type(4))) float f32x4;

__device__ __forceinline__ unsigned short f2bf(float f) {
  unsigned int u = __float_as_uint(f);
  return (unsigned short)((u + 0x7fffu + ((u >> 16) & 1u)) >> 16);
}

__global__ void xcast_kernel(const float* __restrict__ x, unsigned short* __restrict__ xb) {
  int idx = (blockIdx.x * blockDim.x + threadIdx.x) * 8;
  const float4* xp = (const float4*)(x + idx);
  float4 a = xp[0], b = xp[1];
  uint4 o;
  o.x = (unsigned)f2bf(a.x) | ((unsigned)f2bf(a.y) << 16);
  o.y = (unsigned)f2bf(a.z) | ((unsigned)f2bf(a.w) << 16);
  o.z = (unsigned)f2bf(b.x) | ((unsigned)f2bf(b.y) << 16);
  o.w = (unsigned)f2bf(b.z) | ((unsigned)f2bf(b.w) << 16);
  *(uint4*)(xb + idx) = o;
}

// Block tile 128(M) x 128(N), 4 waves; wave w owns cols n0+w*32..+32, all 128 rows.
// x: LDS staging (R4-verbatim addressing), now 4 buffers, stage-ahead +2.
// W: reg-direct dwordx4 nibble path (R4-verbatim), prefetch-ahead +1.
// Sync: counted s_waitcnt vmcnt(16) + raw s_barrier — never drain to 0 (T3/T4).
__global__ __launch_bounds__(256, 2)
void gemm_kernel(const unsigned short* __restrict__ xb,
                 const int* __restrict__ wq,
                 const float* __restrict__ scale,
                 const float* __restrict__ zpt,
                 unsigned short* __restrict__ partial)
{
  __shared__ uint4 xbuf[4][1024];    // 4 x 16 KB

  const int tid = threadIdx.x;
  const int l   = tid & 63;
  const int w   = tid >> 6;
  const int l15 = l & 15;
  const int lk  = l >> 4;            // 0..3
  const int n0  = blockIdx.x * 128;
  const int ks  = blockIdx.y;
  const int k0  = ks * KCHUNK;

  const int r0 = n0 + w * 32 + l15;  // lane's two weight rows (B-frag cols)
  const int r1 = r0 + 16;
  const int* wp0 = wq + (size_t)r0 * KP + (k0 >> 1) + lk * 4;
  const int* wp1 = wq + (size_t)r1 * KP + (k0 >> 1) + lk * 4;

  f32x4 acc[8][2];
  #pragma unroll
  for (int mi = 0; mi < 8; ++mi)
    #pragma unroll
    for (int ni = 0; ni < 2; ++ni) {
      f32x4 z = {0.f, 0.f, 0.f, 0.f};
      acc[mi][ni] = z;
    }

  int4  wA[2][2], wB[2][2];          // [ni][kk], statically indexed double-buffer
  float scA[2], nzA[2], scB[2], nzB[2];

  // x staging: linear LDS dest, inverse-swizzled global source (R4-verbatim)
  auto issue_x = [&](int t, int nb) {
    const int kt = k0 + t * BK;
    #pragma unroll
    for (int i = 0; i < 4; ++i) {
      int rloc = i * 32 + w * 8 + (l >> 3);                    // LDS row 0..127
      const unsigned short* src = xb + (size_t)rloc * K_DIM + kt
                                  + (((l & 7) ^ ((l >> 3) & 7)) * 8);
      uint4* dst = &xbuf[nb][(i * 32 + w * 8) * 8];            // wave-uniform base
      __builtin_amdgcn_global_load_lds(
          (__attribute__((address_space(1))) void*)(void*)src,
          (__attribute__((address_space(3))) void*)(void*)dst, 16, 0, 0);
    }
  };

  // 8 dwordx4 + 4 scale dwords = 12 vmem ops (uniform every step)
  auto LOADW = [&](int t, int4 (&wr)[2][2], float (&sc)[2], float (&nz)[2]) {
    #pragma unroll
    for (int kk = 0; kk < 2; ++kk) {
      wr[0][kk] = *(const int4*)(wp0 + t * 32 + kk * 16);
      wr[1][kk] = *(const int4*)(wp1 + t * 32 + kk * 16);
    }
    const int g = (k0 + t * BK) >> 7;
    float s0 = scale[r0 * NGRP + g], z0 = zpt[r0 * NGRP + g];
    float s1 = scale[r1 * NGRP + g], z1 = zpt[r1 * NGRP + g];
    sc[0] = s0; nz[0] = -z0 * s0;
    sc[1] = s1; nz[1] = -z1 * s1;
  };

  auto COMPUTE = [&](const uint4* xlds, const int4 (&wr)[2][2],
                     const float (&sc)[2], const float (&nz)[2]) {
    #pragma unroll
    for (int kk = 0; kk < 2; ++kk) {
      const int q = kk * 4 + lk;                 // x chunk 0..7 within BK=64 row
      uint4 av[8];
      #pragma unroll
      for (int mi = 0; mi < 8; ++mi) {
        int r = mi * 16 + l15;
        av[mi] = xlds[r * 8 + (q ^ (r & 7))];    // swizzled read (R4-verbatim)
      }
      uint4 bq[2];
      #pragma unroll
      for (int ni = 0; ni < 2; ++ni) {
        int vals[4] = {wr[ni][kk].x, wr[ni][kk].y, wr[ni][kk].z, wr[ni][kk].w};
        unsigned words[4];
        #pragma unroll
        for (int j = 0; j < 4; ++j) {
          int hi = (vals[j] << 24) >> 28;        // bits 7:4 -> k even
          int lo = (vals[j] << 28) >> 28;        // bits 3:0 -> k odd
          float fh = fmaf((float)hi, sc[ni], nz[ni]);
          float fl = fmaf((float)lo, sc[ni], nz[ni]);
          unsigned r;
          asm("v_cvt_pk_bf16_f32 %0, %1, %2" : "=v"(r) : "v"(fh), "v"(fl));
          words[j] = r;
        }
        uint4 o; o.x = words[0]; o.y = words[1]; o.z = words[2]; o.w = words[3];
        bq[ni] = o;
      }
      #pragma unroll
      for (int mi = 0; mi < 8; ++mi)
        #pragma unroll
        for (int ni = 0; ni < 2; ++ni)
          acc[mi][ni] = __builtin_amdgcn_mfma_f32_16x16x32_bf16(
              __builtin_bit_cast(bf16x8, av[mi]),
              __builtin_bit_cast(bf16x8, bq[ni]),
              acc[mi][ni], 0, 0, 0);
    }
  };

  // prologue — issue order matters for the vmcnt window accounting:
  // [S(0):4][S(1):4][L(0):12] ; each loop half then issues exactly 16 more.
  issue_x(0, 0);
  issue_x(1, 1);
  LOADW(0, wA, scA, nzA);

  for (int t = 0; t < NSTEPS; t += 2) {
    // even half: prefetch S(t+2), L(t+1); consume S(t), L(t)
    issue_x(t + 2 < NSTEPS ? t + 2 : NSTEPS - 1, (t + 2) & 3);
    LOADW(t + 1 < NSTEPS ? t + 1 : NSTEPS - 1, wB, scB, nzB);
    asm volatile("s_waitcnt vmcnt(16)" ::: "memory");  // retire through L(t); keep newest 16
    __builtin_amdgcn_s_barrier();
    COMPUTE(&xbuf[t & 3][0], wA, scA, nzA);

    // odd half: prefetch S(t+3), L(t+2); consume S(t+1), L(t+1)
    issue_x(t + 3 < NSTEPS ? t + 3 : NSTEPS - 1, (t + 3) & 3);
    LOADW(t + 2 < NSTEPS ? t + 2 : NSTEPS - 1, wA, scA, nzA);
    asm volatile("s_waitcnt vmcnt(16)" ::: "memory");  // retire through L(t+1)
    __builtin_amdgcn_s_barrier();
    COMPUTE(&xbuf[(t + 1) & 3][0], wB, scB, nzB);
  }

  // epilogue: bf16 partial [ks][s][o] (R4-verbatim)
  unsigned short* p = partial + (size_t)ks * (M_DIM * N_DIM);
  #pragma unroll
  for (int mi = 0; mi < 8; ++mi)
    #pragma unroll
    for (int ni = 0; ni < 2; ++ni) {
      int col = n0 + w * 32 + ni * 16 + l15;
      int rowb = mi * 16 + lk * 4;
      #pragma unroll
      for (int j = 0; j < 4; ++j)
        p[(size_t)(rowb + j) * N_DIM + col] = f2bf(acc[mi][ni][j]);
    }
}

// reduce over ksplit + bias (R4-verbatim)
__global__ void reduce_kernel(const unsigned short* __restrict__ part,
                              const float* __restrict__ bias,
                              float* __restrict__ out) {
  int idx = (blockIdx.x * blockDim.x + threadIdx.x) * 8;
  float s[8];
  #pragma unroll
  for (int j = 0; j < 8; ++j) s[j] = 0.f;
  #pragma unroll
  for (int k = 0; k < KSPLIT; ++k) {
    uint4 v = *(const uint4*)(part + (size_t)k * (M_DIM * N_DIM) + idx);
    unsigned ws[4] = {v.x, v.y, v.z, v.w};
    #pragma unroll
    for (int j = 0; j < 4; ++j) {
      s[2 * j]     += __uint_as_float((ws[j] & 0xffffu) << 16);
      s[2 * j + 1] += __uint_as_float(ws[j] & 0xffff0000u);
    }
  }
  int col = idx & (N_DIM - 1);
  float4 b0 = *(const float4*)(bias + col);
  float4 b1 = *(const float4*)(bias + col + 4);
  float4 o0, o1;
  o0.x = s[0] + b0.x; o0.y = s[1] + b0.y; o0.z = s[2] + b0.z; o0.w = s[3] + b0.w;
  o1.x = s[4] + b1.x; o1.y = s[5] + b1.y; o1.z = s[6] + b1.z; o1.w = s[7] + b1.w;
  *(float4*)(out + idx) = o0;
  *(float4*)(out + idx + 4) = o1;
}

extern "C" void kernel_launch(void* const* d_in, const int* in_sizes, int n_in,
                              void* d_out, int out_size, void* d_ws, size_t ws_size,
                              hipStream_t stream) {
  const float* x     = (const float*)d_in[0];
  const int*   wq    = (const int*)d_in[1];
  const float* scale = (const float*)d_in[2];
  const float* zpt   = (const float*)d_in[3];
  const float* bias  = (const float*)d_in[4];
  float* out = (float*)d_out;

  unsigned short* xb = (unsigned short*)d_ws;
  const size_t xbytes = (size_t)M_DIM * K_DIM * 2;                   // 2 MiB
  unsigned short* partial = (unsigned short*)((char*)d_ws + xbytes); // 16 MiB bf16

  xcast_kernel<<<(M_DIM * K_DIM) / (256 * 8), 256, 0, stream>>>(x, xb);
  gemm_kernel<<<dim3(N_DIM / 128, KSPLIT), 256, 0, stream>>>(
      xb, wq, scale, zpt, partial);
  reduce_kernel<<<(M_DIM * N_DIM) / (256 * 8), 256, 0, stream>>>(
      partial, bias, out);
}

// Round 6
// 54.543 us; speedup vs baseline: 1.7950x; 1.0466x over previous
//
#include <hip/hip_runtime.h>
#include <hip/hip_bf16.h>
#include <stdint.h>

#define M_DIM 128
#define N_DIM 8192
#define K_DIM 8192
#define KP    4096      // packed int32 per weight row
#define NGRP  64
#define KSPLIT 8
#define KCHUNK (K_DIM / KSPLIT)   // 1024
#define BK    64
#define NSTEPS (KCHUNK / BK)      // 16
#define NMEGA  4                  // mega-steps (256 k each)

typedef __attribute__((ext_vector_type(8))) short bf16x8;
typedef __attribute__((ext_vector_type(4))) float f32x4;

__device__ __forceinline__ unsigned short f2bf(float f) {
  unsigned int u = __float_as_uint(f);
  return (unsigned short)((u + 0x7fffu + ((u >> 16) & 1u)) >> 16);
}

__global__ void xcast_kernel(const float* __restrict__ x, unsigned short* __restrict__ xb) {
  int idx = (blockIdx.x * blockDim.x + threadIdx.x) * 8;
  const float4* xp = (const float4*)(x + idx);
  float4 a = xp[0], b = xp[1];
  uint4 o;
  o.x = (unsigned)f2bf(a.x) | ((unsigned)f2bf(a.y) << 16);
  o.y = (unsigned)f2bf(a.z) | ((unsigned)f2bf(a.w) << 16);
  o.z = (unsigned)f2bf(b.x) | ((unsigned)f2bf(b.y) << 16);
  o.w = (unsigned)f2bf(b.z) | ((unsigned)f2bf(b.w) << 16);
  *(uint4*)(xb + idx) = o;
}

// Block 128(M)x128(N), 4 waves. x: R4-verbatim LDS staging.
// W: mega-step (256k) coalesced loads (2 rows x 512B per wave-instr),
//    nibble-pack 16B->4B in regs, ds_write packed, swizzled ds_read fragments.
__global__ __launch_bounds__(256, 2)
void gemm_kernel(const unsigned short* __restrict__ xb,
                 const int* __restrict__ wq,
                 const float* __restrict__ scale,
                 const float* __restrict__ zpt,
                 unsigned short* __restrict__ partial)
{
  __shared__ uint4 xbuf[2][1024];        // 2 x 16 KB
  __shared__ unsigned wlds[2][128 * 32]; // 2 x 16 KB packed nibbles

  const int tid = threadIdx.x;
  const int l   = tid & 63;
  const int w   = tid >> 6;
  const int l15 = l & 15;
  const int lk  = l >> 4;
  const int n0  = blockIdx.x * 128;
  const int ks  = blockIdx.y;
  const int k0  = ks * KCHUNK;

  // coalesced W-load mapping: instr j covers rows {w*32+2j, +1}, 512B each
  const int wrow_base = w * 32 + (l >> 5);     // + 2j
  const int wcol16    = l & 31;                // 16B chunk within row's 512B

  // fragment rows (dequant/scales/output cols)
  const int r0 = n0 + w * 32 + l15;
  const int r1 = r0 + 16;

  f32x4 acc[8][2];
  #pragma unroll
  for (int mi = 0; mi < 8; ++mi)
    #pragma unroll
    for (int ni = 0; ni < 2; ++ni) {
      f32x4 z = {0.f, 0.f, 0.f, 0.f};
      acc[mi][ni] = z;
    }

  int4  raw[16];                 // one mega-step of raw weights (64 VGPR)
  float scs[2][2][2], nzs[2][2][2];   // [buf][ni][grp] — all static after unroll

  const int* wbase = wq + (size_t)(n0 + wrow_base) * KP + (k0 >> 1) + wcol16 * 4;

  auto WLOAD = [&](int T, int sb) {
    #pragma unroll
    for (int j = 0; j < 16; ++j)
      raw[j] = *(const int4*)(wbase + (size_t)2 * j * KP + T * 128);
    const int g0 = (k0 + T * 256) >> 7;
    #pragma unroll
    for (int gi = 0; gi < 2; ++gi) {
      float s0 = scale[r0 * NGRP + g0 + gi], z0 = zpt[r0 * NGRP + g0 + gi];
      float s1 = scale[r1 * NGRP + g0 + gi], z1 = zpt[r1 * NGRP + g0 + gi];
      scs[sb][0][gi] = s0; nzs[sb][0][gi] = -z0 * s0;
      scs[sb][1][gi] = s1; nzs[sb][1][gi] = -z1 * s1;
    }
  };

  auto PACKW = [&](int wb) {
    #pragma unroll
    for (int j = 0; j < 16; ++j) {
      unsigned p = ((unsigned)raw[j].x & 0xffu)
                 | (((unsigned)raw[j].y & 0xffu) << 8)
                 | (((unsigned)raw[j].z & 0xffu) << 16)
                 | (((unsigned)raw[j].w) << 24);
      int row = wrow_base + 2 * j;
      wlds[wb][row * 32 + (wcol16 ^ ((row & 15) << 1))] = p;
    }
  };

  // x staging: R4-verbatim (linear LDS dest, inverse-swizzled global src)
  auto issue_x = [&](int t, int nb) {
    const int kt = k0 + t * BK;
    #pragma unroll
    for (int i = 0; i < 4; ++i) {
      int rloc = i * 32 + w * 8 + (l >> 3);
      const unsigned short* src = xb + (size_t)rloc * K_DIM + kt
                                  + (((l & 7) ^ ((l >> 3) & 7)) * 8);
      uint4* dst = &xbuf[nb][(i * 32 + w * 8) * 8];
      __builtin_amdgcn_global_load_lds(
          (__attribute__((address_space(1))) void*)(void*)src,
          (__attribute__((address_space(3))) void*)(void*)dst, 16, 0, 0);
    }
  };

  auto COMPUTE = [&](const uint4* xlds, const unsigned* wb_lds, int tsub, int sb) {
    const int gi = tsub >> 1;
    #pragma unroll
    for (int kk = 0; kk < 2; ++kk) {
      const int q = kk * 4 + lk;
      uint4 av[8];
      #pragma unroll
      for (int mi = 0; mi < 8; ++mi) {
        int r = mi * 16 + l15;
        av[mi] = xlds[r * 8 + (q ^ (r & 7))];
      }
      const int c = tsub * 8 + kk * 4 + lk;
      unsigned pk[2];
      pk[0] = wb_lds[(w * 32 + l15) * 32      + (c ^ (l15 << 1))];
      pk[1] = wb_lds[(w * 32 + l15 + 16) * 32 + (c ^ (l15 << 1))];
      uint4 bq[2];
      #pragma unroll
      for (int ni = 0; ni < 2; ++ni) {
        unsigned words[4];
        #pragma unroll
        for (int j = 0; j < 4; ++j) {
          int hi = ((int)(pk[ni] << (24 - 8 * j))) >> 28;  // byte j bits 7:4
          int lo = ((int)(pk[ni] << (28 - 8 * j))) >> 28;  // byte j bits 3:0
          float fh = fmaf((float)hi, scs[sb][ni][gi], nzs[sb][ni][gi]);
          float fl = fmaf((float)lo, scs[sb][ni][gi], nzs[sb][ni][gi]);
          asm("v_cvt_pk_bf16_f32 %0, %1, %2" : "=v"(words[j]) : "v"(fh), "v"(fl));
        }
        uint4 o; o.x = words[0]; o.y = words[1]; o.z = words[2]; o.w = words[3];
        bq[ni] = o;
      }
      #pragma unroll
      for (int mi = 0; mi < 8; ++mi)
        #pragma unroll
        for (int ni = 0; ni < 2; ++ni)
          acc[mi][ni] = __builtin_amdgcn_mfma_f32_16x16x32_bf16(
              __builtin_bit_cast(bf16x8, av[mi]),
              __builtin_bit_cast(bf16x8, bq[ni]),
              acc[mi][ni], 0, 0, 0);
    }
  };

  // prologue
  WLOAD(0, 0);
  issue_x(0, 0);
  PACKW(0);            // waits raw(0) via data dep
  WLOAD(1, 1);         // mega-1 loads fly during mega-0 compute
  __syncthreads();     // wlds[0] + xbuf[0] visible

  #pragma unroll
  for (int T = 0; T < NMEGA; ++T) {
    #pragma unroll
    for (int tsub = 0; tsub < 4; ++tsub) {
      const int t = T * 4 + tsub;
      if (t + 1 < NSTEPS) issue_x(t + 1, (t + 1) & 1);
      COMPUTE(&xbuf[t & 1][0], &wlds[T & 1][0], tsub, T & 1);
      if (tsub == 3 && T + 1 < NMEGA) {
        PACKW((T + 1) & 1);                       // raw(T+1) long since landed
        if (T + 2 < NMEGA) WLOAD(T + 2, (T + 2) & 1);
      }
      __syncthreads();
    }
  }

  // epilogue: bf16 partial [ks][s][o] (R4-verbatim)
  unsigned short* p = partial + (size_t)ks * (M_DIM * N_DIM);
  #pragma unroll
  for (int mi = 0; mi < 8; ++mi)
    #pragma unroll
    for (int ni = 0; ni < 2; ++ni) {
      int col = n0 + w * 32 + ni * 16 + l15;
      int rowb = mi * 16 + lk * 4;
      #pragma unroll
      for (int j = 0; j < 4; ++j)
        p[(size_t)(rowb + j) * N_DIM + col] = f2bf(acc[mi][ni][j]);
    }
}

// reduce over ksplit + bias (R4-verbatim)
__global__ void reduce_kernel(const unsigned short* __restrict__ part,
                              const float* __restrict__ bias,
                              float* __restrict__ out) {
  int idx = (blockIdx.x * blockDim.x + threadIdx.x) * 8;
  float s[8];
  #pragma unroll
  for (int j = 0; j < 8; ++j) s[j] = 0.f;
  #pragma unroll
  for (int k = 0; k < KSPLIT; ++k) {
    uint4 v = *(const uint4*)(part + (size_t)k * (M_DIM * N_DIM) + idx);
    unsigned ws[4] = {v.x, v.y, v.z, v.w};
    #pragma unroll
    for (int j = 0; j < 4; ++j) {
      s[2 * j]     += __uint_as_float((ws[j] & 0xffffu) << 16);
      s[2 * j + 1] += __uint_as_float(ws[j] & 0xffff0000u);
    }
  }
  int col = idx & (N_DIM - 1);
  float4 b0 = *(const float4*)(bias + col);
  float4 b1 = *(const float4*)(bias + col + 4);
  float4 o0, o1;
  o0.x = s[0] + b0.x; o0.y = s[1] + b0.y; o0.z = s[2] + b0.z; o0.w = s[3] + b0.w;
  o1.x = s[4] + b1.x; o1.y = s[5] + b1.y; o1.z = s[6] + b1.z; o1.w = s[7] + b1.w;
  *(float4*)(out + idx) = o0;
  *(float4*)(out + idx + 4) = o1;
}

extern "C" void kernel_launch(void* const* d_in, const int* in_sizes, int n_in,
                              void* d_out, int out_size, void* d_ws, size_t ws_size,
                              hipStream_t stream) {
  const float* x     = (const float*)d_in[0];
  const int*   wq    = (const int*)d_in[1];
  const float* scale = (const float*)d_in[2];
  const float* zpt   = (const float*)d_in[3];
  const float* bias  = (const float*)d_in[4];
  float* out = (float*)d_out;

  unsigned short* xb = (unsigned short*)d_ws;
  const size_t xbytes = (size_t)M_DIM * K_DIM * 2;                   // 2 MiB
  unsigned short* partial = (unsigned short*)((char*)d_ws + xbytes); // 16 MiB bf16

  xcast_kernel<<<(M_DIM * K_DIM) / (256 * 8), 256, 0, stream>>>(x, xb);
  gemm_kernel<<<dim3(N_DIM / 128, KSPLIT), 256, 0, stream>>>(
      xb, wq, scale, zpt, partial);
  reduce_kernel<<<(M_DIM * N_DIM) / (256 * 8), 256, 0, stream>>>(
      partial, bias, out);
}